// Round 1
// baseline (453.992 us; speedup 1.0000x reference)
//
#include <hip/hip_runtime.h>
#include <hip/hip_bf16.h>
#include <math.h>

#define BATCH 32
#define SEQ_Q 2048
#define SEQ_K 2048
#define DIM   128
#define QTILE 64
#define KVB   32
#define VSTR  36   // Vt kv-stride in elems (72B: 8B-aligned reads, spread write banks)
#define PSTR  40   // P q-stride in elems (80B: 16B-aligned A-frag reads)

typedef __bf16 bf16_t;
typedef __attribute__((ext_vector_type(4))) __bf16 bf4;
typedef __attribute__((ext_vector_type(8))) __bf16 bf8;
typedef __attribute__((ext_vector_type(4))) float f32x4;

static __device__ __forceinline__ f32x4 mfma16(bf8 a, bf8 b, f32x4 c) {
    return __builtin_amdgcn_mfma_f32_16x16x32_bf16(a, b, c, 0, 0, 0);
}

__global__ __launch_bounds__(256, 3)
void attn_fwd(const float* __restrict__ Q, const float* __restrict__ K,
              const float* __restrict__ V, const int* __restrict__ vlen,
              float* __restrict__ O)
{
    __shared__ __align__(128) __bf16 Klds[KVB * DIM];   // row-major, XOR-swizzled
    __shared__ __align__(128) __bf16 Vt[DIM * VSTR];    // transposed [dv][kv]
    __shared__ __align__(128) __bf16 Plds[QTILE * PSTR];

    const int tid  = threadIdx.x;
    const int w    = tid >> 6;        // wave 0..3
    const int lane = tid & 63;
    const int c    = lane & 15;       // frag col / A row
    const int g    = lane >> 4;       // 16-lane group
    const int b    = blockIdx.y;
    const int q0   = blockIdx.x * QTILE;

    const int valid  = vlen[b];
    const int ntiles = (valid + KVB - 1) / KVB;

    // scale folded into Q: 1/sqrt(128) * log2(e)  -> softmax via exp2
    const float QSCALE = 0.08838834764831845f * 1.4426950408889634f;

    // ---- Q fragments: lane holds Q[q0 + w*16 + c][kb*32 + g*8 + i], i=0..7
    bf8 qf[4];
    {
        const float* qp = Q + ((size_t)b * SEQ_Q + q0 + w * 16 + c) * DIM + g * 8;
        #pragma unroll
        for (int kb = 0; kb < 4; ++kb) {
            float4 x = *(const float4*)(qp + kb * 32);
            float4 y = *(const float4*)(qp + kb * 32 + 4);
            bf8 q8;
            q8[0] = (__bf16)(x.x * QSCALE); q8[1] = (__bf16)(x.y * QSCALE);
            q8[2] = (__bf16)(x.z * QSCALE); q8[3] = (__bf16)(x.w * QSCALE);
            q8[4] = (__bf16)(y.x * QSCALE); q8[5] = (__bf16)(y.y * QSCALE);
            q8[6] = (__bf16)(y.z * QSCALE); q8[7] = (__bf16)(y.w * QSCALE);
            qf[kb] = q8;
        }
    }

    f32x4 acc[8];
    #pragma unroll
    for (int i = 0; i < 8; ++i) acc[i] = (f32x4){0.f, 0.f, 0.f, 0.f};
    float m_r[4], l_r[4];
    #pragma unroll
    for (int r = 0; r < 4; ++r) { m_r[r] = -INFINITY; l_r[r] = 0.f; }

    for (int t = 0; t < ntiles; ++t) {
        const int kv0 = t * KVB;
        __syncthreads();   // previous tile fully consumed

        // ---- stage K tile: [KVB][DIM] bf16, swizzled (byte ^= (kv&7)<<4)
        #pragma unroll
        for (int p = 0; p < 4; ++p) {
            int idx = p * 256 + tid;
            int kv = idx >> 5, d4 = idx & 31;
            float4 kx = *(const float4*)(K + ((size_t)b * SEQ_K + kv0 + kv) * DIM + d4 * 4);
            bf4 k4;
            k4[0] = (__bf16)kx.x; k4[1] = (__bf16)kx.y;
            k4[2] = (__bf16)kx.z; k4[3] = (__bf16)kx.w;
            int off = (kv * 256 + d4 * 8) ^ ((kv & 7) << 4);
            *(bf4*)((char*)Klds + off) = k4;
        }
        // ---- stage V tile transposed: Vt[dv][kv]
        #pragma unroll
        for (int p = 0; p < 4; ++p) {
            int idx = p * 256 + tid;
            int kv = idx >> 5, d4 = idx & 31;
            float4 vx = *(const float4*)(V + ((size_t)b * SEQ_K + kv0 + kv) * DIM + d4 * 4);
            __bf16* vt = Vt + (d4 * 4) * VSTR + kv;
            vt[0]        = (__bf16)vx.x;
            vt[VSTR]     = (__bf16)vx.y;
            vt[2 * VSTR] = (__bf16)vx.z;
            vt[3 * VSTR] = (__bf16)vx.w;
        }
        __syncthreads();

        // ---- S = Q K^T (two 16x16 frags: kv = c, c+16)
        f32x4 s0 = (f32x4){0.f, 0.f, 0.f, 0.f};
        f32x4 s1 = (f32x4){0.f, 0.f, 0.f, 0.f};
        #pragma unroll
        for (int kb = 0; kb < 4; ++kb) {
            int off0 = ((c)      * 256 + kb * 64 + g * 16) ^ ((c & 7) << 4);
            int off1 = ((c + 16) * 256 + kb * 64 + g * 16) ^ ((c & 7) << 4);
            bf8 k0 = *(bf8*)((char*)Klds + off0);
            bf8 k1 = *(bf8*)((char*)Klds + off1);
            s0 = mfma16(qf[kb], k0, s0);
            s1 = mfma16(qf[kb], k1, s1);
        }

        // ---- boundary mask (column kv_global >= valid -> -inf)
        if (kv0 + KVB > valid) {
            if (kv0 + c >= valid) {
                s0[0] = -INFINITY; s0[1] = -INFINITY; s0[2] = -INFINITY; s0[3] = -INFINITY;
            }
            if (kv0 + 16 + c >= valid) {
                s1[0] = -INFINITY; s1[1] = -INFINITY; s1[2] = -INFINITY; s1[3] = -INFINITY;
            }
        }

        // ---- online softmax (rows = 4g + r), exp2 domain
        float pr0[4], pr1[4], alpha[4];
        #pragma unroll
        for (int r = 0; r < 4; ++r) {
            float mt = fmaxf(s0[r], s1[r]);
            mt = fmaxf(mt, __shfl_xor(mt, 1));
            mt = fmaxf(mt, __shfl_xor(mt, 2));
            mt = fmaxf(mt, __shfl_xor(mt, 4));
            mt = fmaxf(mt, __shfl_xor(mt, 8));
            float mn = fmaxf(m_r[r], mt);
            alpha[r] = exp2f(m_r[r] - mn);
            m_r[r] = mn;
            pr0[r] = exp2f(s0[r] - mn);
            pr1[r] = exp2f(s1[r] - mn);
            float rs = pr0[r] + pr1[r];
            rs += __shfl_xor(rs, 1);
            rs += __shfl_xor(rs, 2);
            rs += __shfl_xor(rs, 4);
            rs += __shfl_xor(rs, 8);
            l_r[r] = l_r[r] * alpha[r] + rs;
        }
        #pragma unroll
        for (int dvb = 0; dvb < 8; ++dvb) {
            #pragma unroll
            for (int r = 0; r < 4; ++r) acc[dvb][r] *= alpha[r];
        }

        // ---- P -> LDS (per-wave region, C-layout scatter), then A-frag read
        {
            __bf16* pw = Plds + (size_t)(w * 16 + g * 4) * PSTR;
            #pragma unroll
            for (int r = 0; r < 4; ++r) {
                pw[r * PSTR + c]      = (__bf16)pr0[r];
                pw[r * PSTR + c + 16] = (__bf16)pr1[r];
            }
        }
        bf8 pa = *(bf8*)((char*)Plds + ((size_t)(w * 16 + c) * PSTR + g * 8) * 2);

        // ---- O += P V
        #pragma unroll
        for (int dvb = 0; dvb < 8; ++dvb) {
            const __bf16* vp = Vt + (size_t)(dvb * 16 + c) * VSTR + g * 8;
            bf4 vlo = *(const bf4*)(vp);
            bf4 vhi = *(const bf4*)(vp + 4);
            bf8 vb = __builtin_shufflevector(vlo, vhi, 0, 1, 2, 3, 4, 5, 6, 7);
            acc[dvb] = mfma16(pa, vb, acc[dvb]);
        }
    }

    // ---- epilogue: normalize and store fp32
    float inv[4];
    #pragma unroll
    for (int r = 0; r < 4; ++r) inv[r] = 1.0f / l_r[r];
    float* op = O + ((size_t)b * SEQ_Q + q0 + w * 16 + g * 4) * DIM + c;
    #pragma unroll
    for (int dvb = 0; dvb < 8; ++dvb) {
        #pragma unroll
        for (int r = 0; r < 4; ++r)
            op[(size_t)r * DIM + dvb * 16] = acc[dvb][r] * inv[r];
    }
}

extern "C" void kernel_launch(void* const* d_in, const int* in_sizes, int n_in,
                              void* d_out, int out_size, void* d_ws, size_t ws_size,
                              hipStream_t stream) {
    const float* Q  = (const float*)d_in[0];
    const float* K  = (const float*)d_in[1];
    const float* V  = (const float*)d_in[2];
    const int*   vl = (const int*)d_in[3];
    float* O = (float*)d_out;
    dim3 grid(SEQ_Q / QTILE, BATCH);
    attn_fwd<<<grid, dim3(256), 0, stream>>>(Q, K, V, vl, O);
}

// Round 5
// 219.862 us; speedup vs baseline: 2.0649x; 2.0649x over previous
//
#include <hip/hip_runtime.h>
#include <hip/hip_bf16.h>
#include <math.h>

// Flash attention fwd, B=32, LQ=LK=2048, D=128, fp32 in/out, per-batch valid_len mask.
// Structure (guide §B m214-style): swapped QK^T (S^T = mfma(K,Q)) so each lane owns
// one q-row's P values -> lane-local softmax; PV as mfma(A=V^T-frag, B=P-frag) keeps
// acc in q=lane&31 orientation (per-lane alpha rescale / l-normalize).
// KVB=64, K/V double-buffered in LDS (64KB total), async reg-staged fp32->bf16.
// R3 fix: V tile load used kvA = kv0+8*i+2*tw (kv 40..63 never staged -> uninit LDS
// -> NaN). Correct stride: kvA = kv0+16*i+2*tw, STORE pair p = 8*i+tw.

#define BATCH 32
#define SEQL  2048
#define DIM   128
#define KVB   64
#define QTILE 128
#define KBUF  16384
#define VBUF  16384
#define EPSTR 34

typedef __attribute__((ext_vector_type(8)))  __bf16 bf8;
typedef __attribute__((ext_vector_type(16))) float  f16v;
typedef __attribute__((ext_vector_type(2)))  unsigned int u32x2;
typedef unsigned int u32;

static __device__ __forceinline__ f16v mfma32(bf8 a, bf8 b, f16v c) {
  return __builtin_amdgcn_mfma_f32_32x32x16_bf16(a, b, c, 0, 0, 0);
}
static __device__ __forceinline__ u32 cvtpk(float lo, float hi) {
  u32 r; asm("v_cvt_pk_bf16_f32 %0, %1, %2" : "=v"(r) : "v"(lo), "v"(hi)); return r;
}
static __device__ __forceinline__ void plswap(u32& a, u32& b) {
#if __has_builtin(__builtin_amdgcn_permlane32_swap)
  auto r = __builtin_amdgcn_permlane32_swap(a, b, false, false);
  a = (u32)r[0]; b = (u32)r[1];
#else
  asm("s_nop 1\n\tv_permlane32_swap_b32 %0, %1" : "+v"(a), "+v"(b));
#endif
}
static __device__ __forceinline__ float xmax(float x) {
  u32 a = __builtin_bit_cast(u32, x), c = a;
  plswap(a, c);
  return fmaxf(__builtin_bit_cast(float, a), __builtin_bit_cast(float, c));
}
static __device__ __forceinline__ float xadd(float x) {
  u32 a = __builtin_bit_cast(u32, x), c = a;
  plswap(a, c);
  return __builtin_bit_cast(float, a) + __builtin_bit_cast(float, c);
}
static __device__ __forceinline__ float fexp2(float x) {
#if __has_builtin(__builtin_amdgcn_exp2f)
  return __builtin_amdgcn_exp2f(x);
#else
  return exp2f(x);
#endif
}
static __device__ __forceinline__ u32 ext16(u32x2 v, int c) {
  u32 w = ((c >> 1) & 1) ? v[1] : v[0];   // constant indices in both arms (rule #20)
  return (c & 1) ? (w >> 16) : (w & 0xffffu);
}

// build one PV B-frag (16 kv x 32 q) from 8 in-lane P values (T12 recipe)
#define MKPB(ARR, BASE, DST) {                                   \
    u32 x0 = cvtpk(ARR[BASE+0], ARR[BASE+1]);                    \
    u32 y0 = cvtpk(ARR[BASE+4], ARR[BASE+5]);                    \
    plswap(x0, y0);                                              \
    u32 x1 = cvtpk(ARR[BASE+2], ARR[BASE+3]);                    \
    u32 y1 = cvtpk(ARR[BASE+6], ARR[BASE+7]);                    \
    plswap(x1, y1);                                              \
    union { u32 u[4]; bf8 v; } uu;                               \
    uu.u[0] = x0; uu.u[1] = x1; uu.u[2] = y0; uu.u[3] = y1;      \
    DST = uu.v; }

__global__ __launch_bounds__(256, 2)
void attn_fwd(const float* __restrict__ Q, const float* __restrict__ K,
              const float* __restrict__ V, const int* __restrict__ vlen,
              float* __restrict__ O)
{
  __shared__ __align__(128) char smem[2*KBUF + 2*VBUF];   // 64 KB

  const int tid  = threadIdx.x;
  const int w    = tid >> 6;
  const int lane = tid & 63;
  const int ql   = lane & 31;
  const int hi   = lane >> 5;
  const int tw   = tid >> 5;       // 0..7
  const int d4   = tid & 31;

  // XCD-aware decode: XCD x gets batches 4x..4x+3 entirely (K/V L2 locality)
  const int fid  = blockIdx.x;
  const int bb   = (fid & 7) * 4 + ((fid >> 3) >> 4);
  const int q0   = ((fid >> 3) & 15) * QTILE;

  const int valid = vlen[bb];
  const int nt    = (valid + KVB - 1) / KVB;

  // fold 1/sqrt(128) * log2(e) into Q -> softmax in exp2 domain
  const float QS = 0.08838834764831845f * 1.4426950408889634f;

  // ---- Q B-fragments: lane holds Q[q0+w*32+ql][kb*16 + hi*8 + e], e=0..7
  bf8 qf[8];
  {
    const float* qp = Q + ((size_t)bb * SEQL + q0 + w*32 + ql) * DIM + hi*8;
    #pragma unroll
    for (int kb = 0; kb < 8; ++kb) {
      float4 a = *(const float4*)(qp + kb*16);
      float4 c = *(const float4*)(qp + kb*16 + 4);
      union { u32 u[4]; bf8 v; } t;
      t.u[0] = cvtpk(a.x*QS, a.y*QS);
      t.u[1] = cvtpk(a.z*QS, a.w*QS);
      t.u[2] = cvtpk(c.x*QS, c.y*QS);
      t.u[3] = cvtpk(c.z*QS, c.w*QS);
      qf[kb] = t.v;
    }
  }

  f16v acc[4] = {};
  float m = -INFINITY, l = 0.f;

  // staging registers (bf16-converted at load)
  u32x2 kreg[8], vA[4], vB[4];
  const float* Kb = K + ((size_t)bb * SEQL) * DIM;
  const float* Vb = V + ((size_t)bb * SEQL) * DIM;

  auto LOAD = [&](int t) {
    const int kv0 = t * KVB;
    #pragma unroll
    for (int i = 0; i < 8; ++i) {
      float4 x = *(const float4*)(Kb + (size_t)(kv0 + i*8 + tw) * DIM + d4*4);
      kreg[i][0] = cvtpk(x.x, x.y); kreg[i][1] = cvtpk(x.z, x.w);
    }
    #pragma unroll
    for (int i = 0; i < 4; ++i) {
      const int kvA = kv0 + 16*i + 2*tw;          // R3 fix: 16 rows per i step
      float4 x = *(const float4*)(Vb + (size_t)kvA * DIM + d4*4);
      float4 y = *(const float4*)(Vb + (size_t)(kvA + 1) * DIM + d4*4);
      vA[i][0] = cvtpk(x.x, x.y); vA[i][1] = cvtpk(x.z, x.w);
      vB[i][0] = cvtpk(y.x, y.y); vB[i][1] = cvtpk(y.z, y.w);
    }
  };

  const int kwb = tw*256 + ((d4*8) ^ (tw << 4));  // K LDS write offset (swizzled)
  auto STORE = [&](int s) {
    char* kb_ = smem + s*KBUF;
    char* vb_ = smem + 2*KBUF + s*VBUF;
    #pragma unroll
    for (int i = 0; i < 8; ++i)
      *(u32x2*)(kb_ + i*2048 + kwb) = kreg[i];
    #pragma unroll
    for (int i = 0; i < 4; ++i) {
      const int p = 8*i + tw;            // R3 fix: kv pair index 0..31, kv = {2p, 2p+1}
      #pragma unroll
      for (int j = 0; j < 4; ++j) {
        const int c   = (j + (d4 >> 2)) & 3;   // row-phase rotation (bank spread)
        const int row = 4*d4 + c;              // Vt row = d
        u32 val = ext16(vA[i], c) | (ext16(vB[i], c) << 16);
        *(u32*)(vb_ + row*128 + ((4*p) ^ ((row & 7) << 4))) = val;
      }
    }
  };

  LOAD(0); STORE(0);
  __syncthreads();

  for (int t = 0; t < nt; ++t) {
    const int  sel  = t & 1;
    const bool more = (t + 1 < nt);
    if (more) LOAD(t + 1);             // async: issue next tile's global loads

    const char* kb_ = smem + sel*KBUF;
    const char* vb_ = smem + 2*KBUF + sel*VBUF;

    // ---- S^T = K Q^T : two 32-kv tiles, acc col = q (lane&31), row = kv
    f16v s0v = {}, s1v = {};
    {
      const int rb = ql * 256;
      #pragma unroll
      for (int kb = 0; kb < 8; ++kb) {
        const int off = rb + (((kb << 5) | (hi << 4)) ^ ((ql & 7) << 4));
        bf8 k0 = *(const bf8*)(kb_ + off);
        bf8 k1 = *(const bf8*)(kb_ + off + 8192);   // +32 kv rows
        s0v = mfma32(k0, qf[kb], s0v);
        s1v = mfma32(k1, qf[kb], s1v);
      }
    }

    const int kv0 = t * KVB;
    if (kv0 + KVB > valid) {           // boundary tile mask
      #pragma unroll
      for (int r = 0; r < 16; ++r) {
        const int kvl = (r & 3) + 8*(r >> 2) + 4*hi;
        if (kv0 + kvl >= valid)      s0v[r] = -INFINITY;
        if (kv0 + 32 + kvl >= valid) s1v[r] = -INFINITY;
      }
    }

    // ---- lane-local online softmax (q = lane&31; kv split across lane half-pair)
    float c0 = fmaxf(s0v[0], s1v[0]);
    float c1 = fmaxf(s0v[1], s1v[1]);
    float c2 = fmaxf(s0v[2], s1v[2]);
    float c3 = fmaxf(s0v[3], s1v[3]);
    #pragma unroll
    for (int r = 4; r < 16; r += 4) {
      c0 = fmaxf(c0, fmaxf(s0v[r],     s1v[r]));
      c1 = fmaxf(c1, fmaxf(s0v[r + 1], s1v[r + 1]));
      c2 = fmaxf(c2, fmaxf(s0v[r + 2], s1v[r + 2]));
      c3 = fmaxf(c3, fmaxf(s0v[r + 3], s1v[r + 3]));
    }
    const float tmax = xmax(fmaxf(fmaxf(c0, c1), fmaxf(c2, c3)));

    if (!__all(tmax <= m + 8.0f)) {    // defer-max (T13), THR=8 in exp2 domain
      const float mn = fmaxf(m, tmax);
      const float al = fexp2(m - mn);
      #pragma unroll
      for (int d = 0; d < 4; ++d) acc[d] *= al;
      l *= al;
      m = mn;
    }

    float p0[16], p1[16];
    #pragma unroll
    for (int r = 0; r < 16; ++r) {
      p0[r] = fexp2(s0v[r] - m);
      p1[r] = fexp2(s1v[r] - m);
    }
    {
      float d0 = p0[0] + p1[0], d1 = p0[1] + p1[1];
      float d2 = p0[2] + p1[2], d3 = p0[3] + p1[3];
      #pragma unroll
      for (int r = 4; r < 16; r += 4) {
        d0 += p0[r]     + p1[r];
        d1 += p0[r + 1] + p1[r + 1];
        d2 += p0[r + 2] + p1[r + 2];
        d3 += p0[r + 3] + p1[r + 3];
      }
      l += xadd((d0 + d1) + (d2 + d3));
    }

    // ---- P -> bf16 B-frags in-register (cvt_pk + permlane32_swap)
    bf8 pb[4];
    MKPB(p0, 0, pb[0]); MKPB(p0, 8, pb[1]);
    MKPB(p1, 0, pb[2]); MKPB(p1, 8, pb[3]);

    // ---- O^T += V^T P : acc col = q (lane&31), row = d
    #pragma unroll
    for (int db = 0; db < 4; ++db) {
      #pragma unroll
      for (int ks = 0; ks < 4; ++ks) {
        const int off = (db*32 + ql)*128 + (((ks << 5) | (hi << 4)) ^ ((ql & 7) << 4));
        bf8 vf = *(const bf8*)(vb_ + off);
        acc[db] = mfma32(vf, pb[ks], acc[db]);
      }
    }

    if (more) STORE(sel ^ 1);          // write next tile into other buffer
    __syncthreads();
  }

  // ---- epilogue: normalize, transpose via LDS (per-wave region), coalesced store
  const float invl = 1.0f / l;
  float* ep = (float*)smem + (size_t)w * (32 * EPSTR);
  const size_t orow0 = (size_t)bb * SEQL + q0 + w*32;
  #pragma unroll
  for (int db = 0; db < 4; ++db) {
    #pragma unroll
    for (int r = 0; r < 16; ++r) {
      const int dloc = (r & 3) + 8*(r >> 2) + 4*hi;
      ep[ql*EPSTR + dloc] = acc[db][r] * invl;
    }
    #pragma unroll
    for (int pq = 0; pq < 4; ++pq) {
      const int qr = (lane >> 3) + pq*8;
      const float* rp = ep + qr*EPSTR + (lane & 7)*4;
      float2 x0 = *(const float2*)rp;
      float2 x1 = *(const float2*)(rp + 2);
      float4 st = make_float4(x0.x, x0.y, x1.x, x1.y);
      *(float4*)(O + (orow0 + qr)*DIM + db*32 + (lane & 7)*4) = st;
    }
  }
}

extern "C" void kernel_launch(void* const* d_in, const int* in_sizes, int n_in,
                              void* d_out, int out_size, void* d_ws, size_t ws_size,
                              hipStream_t stream) {
  const float* Q  = (const float*)d_in[0];
  const float* K  = (const float*)d_in[1];
  const float* V  = (const float*)d_in[2];
  const int*   vl = (const int*)d_in[3];
  float* O = (float*)d_out;
  attn_fwd<<<dim3(512), dim3(256), 0, stream>>>(Q, K, V, vl, O);
}